// Round 1
// baseline (153.140 us; speedup 1.0000x reference)
//
#include <hip/hip_runtime.h>
#include <math.h>

#define BATCH   4
#define NPTS    8192
#define THREADS 256
#define QPT     2                        // queries per thread
#define CCHUNKS 4                        // candidate chunks (cross-block min via atomicMin)
#define QBLOCKS (NPTS / (THREADS * QPT)) // 16
#define CHUNK   (NPTS / CCHUNKS)         // 2048
#define NMINS   (2 * BATCH * NPTS)       // 65536 per-query mins

__global__ __launch_bounds__(THREADS) void chamfer_init(unsigned int* __restrict__ wsmin) {
    int i = blockIdx.x * THREADS + threadIdx.x;
    if (i < NMINS) wsmin[i] = 0x7F800000u;  // +inf bits
}

__global__ __launch_bounds__(THREADS) void chamfer_main(const float* __restrict__ preds,
                                                        const float* __restrict__ gts,
                                                        unsigned int* __restrict__ wsmin) {
    const int dir  = blockIdx.z;          // 0: queries=preds, candidates=gts (mins1)
    const int b    = blockIdx.y;
    const int qblk = blockIdx.x / CCHUNKS;
    const int cch  = blockIdx.x % CCHUNKS;

    const float* __restrict__ Q = (dir == 0 ? preds : gts) + (size_t)b * NPTS * 3;
    const float* __restrict__ C = (dir == 0 ? gts : preds) + (size_t)b * NPTS * 3;
    unsigned int* __restrict__ W = wsmin + (dir * BATCH + b) * NPTS;

    const int q0 = qblk * (THREADS * QPT) + threadIdx.x;
    const int q1 = q0 + THREADS;

    const float qx0 = Q[3 * q0], qy0 = Q[3 * q0 + 1], qz0 = Q[3 * q0 + 2];
    const float qx1 = Q[3 * q1], qy1 = Q[3 * q1 + 1], qz1 = Q[3 * q1 + 2];

    // two running mins per query -> 4 independent dep chains
    float mA0 = INFINITY, mB0 = INFINITY, mA1 = INFINITY, mB1 = INFINITY;

    const int jbeg = cch * CHUNK;
    const int jend = jbeg + CHUNK;
#pragma unroll 4
    for (int j = jbeg; j < jend; j += 2) {
        const float cx0 = C[3 * j],     cy0 = C[3 * j + 1], cz0 = C[3 * j + 2];
        const float cx1 = C[3 * j + 3], cy1 = C[3 * j + 4], cz1 = C[3 * j + 5];
        {
            float dx = qx0 - cx0, dy = qy0 - cy0, dz = qz0 - cz0;
            mA0 = fminf(mA0, fmaf(dx, dx, fmaf(dy, dy, dz * dz)));
        }
        {
            float dx = qx1 - cx0, dy = qy1 - cy0, dz = qz1 - cz0;
            mA1 = fminf(mA1, fmaf(dx, dx, fmaf(dy, dy, dz * dz)));
        }
        {
            float dx = qx0 - cx1, dy = qy0 - cy1, dz = qz0 - cz1;
            mB0 = fminf(mB0, fmaf(dx, dx, fmaf(dy, dy, dz * dz)));
        }
        {
            float dx = qx1 - cx1, dy = qy1 - cy1, dz = qz1 - cz1;
            mB1 = fminf(mB1, fmaf(dx, dx, fmaf(dy, dy, dz * dz)));
        }
    }

    const float m0 = fminf(mA0, mB0);
    const float m1 = fminf(mA1, mB1);
    // d^2 >= 0 -> float bit pattern is order-preserving as unsigned; atomicMin is exact/deterministic
    atomicMin(&W[q0], __float_as_uint(m0));
    atomicMin(&W[q1], __float_as_uint(m1));
}

__global__ __launch_bounds__(THREADS) void chamfer_reduce(const unsigned int* __restrict__ wsmin,
                                                          float* __restrict__ out) {
    float s = 0.0f;
    for (int i = threadIdx.x; i < NMINS; i += THREADS) s += __uint_as_float(wsmin[i]);
    // wave64 reduce
    for (int off = 32; off; off >>= 1) s += __shfl_down(s, off, 64);
    __shared__ float sm[THREADS / 64];
    if ((threadIdx.x & 63) == 0) sm[threadIdx.x >> 6] = s;
    __syncthreads();
    if (threadIdx.x == 0) {
        float t = 0.0f;
#pragma unroll
        for (int w = 0; w < THREADS / 64; ++w) t += sm[w];
        out[0] = t / (float)NPTS;  // loss1: sum(mins1)/M + loss2: sum(mins2)/N, M=N=NPTS
    }
}

extern "C" void kernel_launch(void* const* d_in, const int* in_sizes, int n_in,
                              void* d_out, int out_size, void* d_ws, size_t ws_size,
                              hipStream_t stream) {
    const float* preds = (const float*)d_in[0];
    const float* gts   = (const float*)d_in[1];
    float* out = (float*)d_out;
    unsigned int* wsmin = (unsigned int*)d_ws;

    chamfer_init<<<(NMINS + THREADS - 1) / THREADS, THREADS, 0, stream>>>(wsmin);

    dim3 grid(QBLOCKS * CCHUNKS, BATCH, 2);
    chamfer_main<<<grid, THREADS, 0, stream>>>(preds, gts, wsmin);

    chamfer_reduce<<<1, THREADS, 0, stream>>>(wsmin, out);
}

// Round 2
// 80.688 us; speedup vs baseline: 1.8979x; 1.8979x over previous
//
#include <hip/hip_runtime.h>
#include <math.h>

#define BATCH   4
#define NPTS    8192
#define THREADS 256
#define QPT     4                         // queries per thread
#define CCHUNKS 16                        // candidate chunks (cross-block min via atomicMin)
#define CHUNK   (NPTS / CCHUNKS)          // 512
#define QBLOCKS (NPTS / (THREADS * QPT))  // 8
#define NMINS   (2 * BATCH * NPTS)        // 65536 per-query mins
#define NCAND   (2 * BATCH * NPTS)        // 65536 transformed candidates

// ws layout: [0, 1MB) float4 cand; [1MB, 1MB+256KB) uint mins
#define WS_MIN_OFF (NCAND * sizeof(float4))

// Pre-pass: cand[i] = (-2x, -2y, -2z, x^2+y^2+z^2); also init min array to +inf.
// cand dir 0 = gts (candidates for queries=preds), dir 1 = preds.
__global__ __launch_bounds__(THREADS) void chamfer_pre(const float* __restrict__ preds,
                                                       const float* __restrict__ gts,
                                                       float4* __restrict__ cand,
                                                       unsigned int* __restrict__ wsmin) {
    int i = blockIdx.x * THREADS + threadIdx.x;        // 0..65535
    int dir = i >> 15;                                 // 0: gts, 1: preds
    int t = i & 32767;                                 // b*8192 + j
    const float* __restrict__ src = (dir == 0 ? gts : preds);
    float x = src[3 * t], y = src[3 * t + 1], z = src[3 * t + 2];
    cand[i] = make_float4(-2.0f * x, -2.0f * y, -2.0f * z, fmaf(x, x, fmaf(y, y, z * z)));
    wsmin[i] = 0x7F800000u;                            // +inf bits
}

__global__ __launch_bounds__(THREADS) void chamfer_main(const float* __restrict__ preds,
                                                        const float* __restrict__ gts,
                                                        const float4* __restrict__ cand,
                                                        unsigned int* __restrict__ wsmin) {
    const int dir  = blockIdx.z;           // 0: queries=preds, candidates=gts
    const int b    = blockIdx.y;
    const int qblk = blockIdx.x / CCHUNKS;
    const int cch  = blockIdx.x % CCHUNKS;

    const float* __restrict__ Q = (dir == 0 ? preds : gts) + (size_t)b * NPTS * 3;
    const float4* __restrict__ C = cand + (size_t)(dir * BATCH + b) * NPTS + cch * CHUNK;
    unsigned int* __restrict__ W = wsmin + (size_t)(dir * BATCH + b) * NPTS;

    const int q0 = qblk * (THREADS * QPT) + threadIdx.x;

    float qx[QPT], qy[QPT], qz[QPT], rq[QPT], mn[QPT];
#pragma unroll
    for (int k = 0; k < QPT; ++k) {
        int q = q0 + k * THREADS;
        qx[k] = Q[3 * q]; qy[k] = Q[3 * q + 1]; qz[k] = Q[3 * q + 2];
        rq[k] = fmaf(qx[k], qx[k], fmaf(qy[k], qy[k], qz[k] * qz[k]));
        mn[k] = INFINITY;
    }

#pragma unroll 4
    for (int j = 0; j < CHUNK; ++j) {
        const float4 c = C[j];             // wave-uniform -> s_load_dwordx4
#pragma unroll
        for (int k = 0; k < QPT; ++k) {
            float t = fmaf(qx[k], c.x, c.w);
            t = fmaf(qy[k], c.y, t);
            t = fmaf(qz[k], c.z, t);
            mn[k] = fminf(mn[k], t);       // min of (rc - 2*q.c); rq added at end
        }
    }

#pragma unroll
    for (int k = 0; k < QPT; ++k) {
        int q = q0 + k * THREADS;
        float P = fmaxf(rq[k] + mn[k], 0.0f);   // clamp: keep uint-order valid
        atomicMin(&W[q], __float_as_uint(P));   // exact & deterministic
    }
}

__global__ __launch_bounds__(THREADS) void chamfer_reduce(const unsigned int* __restrict__ wsmin,
                                                          float* __restrict__ out) {
    const float4* __restrict__ v = (const float4*)wsmin;  // bits are valid floats (>=0)
    float s = 0.0f;
    int i = threadIdx.x;
#pragma unroll 4
    for (int it = 0; it < NMINS / 4 / THREADS; ++it, i += THREADS) {
        float4 a = v[i];
        s += (a.x + a.y) + (a.z + a.w);
    }
    for (int off = 32; off; off >>= 1) s += __shfl_down(s, off, 64);
    __shared__ float sm[THREADS / 64];
    if ((threadIdx.x & 63) == 0) sm[threadIdx.x >> 6] = s;
    __syncthreads();
    if (threadIdx.x == 0) {
        float t = 0.0f;
#pragma unroll
        for (int w = 0; w < THREADS / 64; ++w) t += sm[w];
        out[0] = t / (float)NPTS;  // sum(mins1)/M + sum(mins2)/N, M=N=NPTS
    }
}

extern "C" void kernel_launch(void* const* d_in, const int* in_sizes, int n_in,
                              void* d_out, int out_size, void* d_ws, size_t ws_size,
                              hipStream_t stream) {
    const float* preds = (const float*)d_in[0];
    const float* gts   = (const float*)d_in[1];
    float* out = (float*)d_out;
    float4* cand = (float4*)d_ws;
    unsigned int* wsmin = (unsigned int*)((char*)d_ws + WS_MIN_OFF);

    chamfer_pre<<<NCAND / THREADS, THREADS, 0, stream>>>(preds, gts, cand, wsmin);

    dim3 grid(QBLOCKS * CCHUNKS, BATCH, 2);
    chamfer_main<<<grid, THREADS, 0, stream>>>(preds, gts, cand, wsmin);

    chamfer_reduce<<<1, THREADS, 0, stream>>>(wsmin, out);
}